// Round 1
// baseline (376.788 us; speedup 1.0000x reference)
//
#include <hip/hip_runtime.h>
#include <math.h>

// LatentSDE: B=8192 independent SDE paths, T=128 steps, H=64 hidden, L=C=D=1.
// Strategy: one 64-lane wave per batch element; lane j owns hidden unit j of
// every MLP. Each MLP = per-lane fma+softplus, then 6-stage shfl_xor sum.
// 8192 waves = 8 waves/SIMD over 256 CUs -> full occupancy.

#define B_SZ 8192
#define T_SZ 128

__device__ __forceinline__ float softplus_f(float x) {
  // stable softplus: max(x,0) + log1p(exp(-|x|)); arg of log in (1,2] so
  // fast __logf is accurate enough here.
  return fmaxf(x, 0.0f) + __logf(1.0f + __expf(-fabsf(x)));
}

__global__ __launch_bounds__(256) void sde_fused(
    const float* __restrict__ xs, const float* __restrict__ ts,
    const float* __restrict__ noise_std, const float* __restrict__ eps0,
    const float* __restrict__ dW,
    const float* __restrict__ ew1, const float* __restrict__ eb1,
    const float* __restrict__ ew2, const float* __restrict__ eb2,
    const float* __restrict__ qw,  const float* __restrict__ qb,
    const float* __restrict__ fw1, const float* __restrict__ fb1,
    const float* __restrict__ fw2, const float* __restrict__ fb2,
    const float* __restrict__ hw1, const float* __restrict__ hb1,
    const float* __restrict__ hw2, const float* __restrict__ hb2,
    const float* __restrict__ gw1, const float* __restrict__ gb1,
    const float* __restrict__ gw2, const float* __restrict__ gb2,
    const float* __restrict__ pw1, const float* __restrict__ pb1,
    const float* __restrict__ pw2, const float* __restrict__ pb2,
    const float* __restrict__ pz0_mean, const float* __restrict__ pz0_logstd,
    float* __restrict__ outA, float* __restrict__ outB)
{
  const int lane = threadIdx.x & 63;
  const int wave = threadIdx.x >> 6;
  const int b = blockIdx.x * 4 + wave;

  // loop-invariant per-lane weights (lane j = hidden unit j)
  const float ew1j = ew1[lane], eb1j = eb1[lane], ew2j = ew2[lane];
  const float fw1z = fw1[lane], fw1c = fw1[64 + lane], fb1j = fb1[lane], fw2j = fw2[lane];
  const float hw1j = hw1[lane], hb1j = hb1[lane], hw2j = hw2[lane];
  const float gw1j = gw1[lane], gb1j = gb1[lane], gw2j = gw2[lane];
  const float pw1j = pw1[lane], pb1j = pb1[lane], pw2j = pw2[lane];
  const float eb2s = eb2[0], fb2s = fb2[0], hb2s = hb2[0], gb2s = gb2[0], pb2s = pb2[0];
  const float qw0 = qw[0], qw1 = qw[1], qb0 = qb[0], qb1 = qb[1];
  const float ns = noise_std[0];
  const float inv_ns = 1.0f / ns;
  const float pm = pz0_mean[0], pls = pz0_logstd[0];

  // ---- z0 from encoder(xs[0]) ----
  const float x0 = xs[b];
  float epre = softplus_f(fmaf(x0, ew1j, eb1j)) * ew2j;
  #pragma unroll
  for (int m = 1; m <= 32; m <<= 1) epre += __shfl_xor(epre, m);
  const float ctx0 = epre + eb2s;
  const float qm  = fmaf(ctx0, qw0, qb0);
  const float qls = fmaf(ctx0, qw1, qb1);
  float z = fmaf(__expf(qls), eps0[b], qm);
  const float dqm = qm - pm;
  const float kl = (pls - qls)
                 + (__expf(2.0f * qls) + dqm * dqm) / (2.0f * __expf(2.0f * pls))
                 - 0.5f;

  float lp_sum, lr_sum = 0.0f;

  // ---- projector likelihood at t=0 ----
  {
    float p = softplus_f(fmaf(z, pw1j, pb1j)) * pw2j;
    #pragma unroll
    for (int m = 1; m <= 32; m <<= 1) p += __shfl_xor(p, m);
    const float px = p + pb2s;
    const float d = (x0 - px) * inv_ns;
    lp_sum = -0.5f * d * d;
  }

  // ---- Euler-Maruyama scan, k = 0..T-2 ----
  for (int k = 0; k < T_SZ - 1; ++k) {
    const float xn   = xs[(k + 1) * B_SZ + b];   // also ctx input (idx = k+1)
    const float dt   = ts[k + 1] - ts[k];        // == 1.0 for arange ts
    const float sqdt = sqrtf(dt);

    // encoder(ctx[k+1]), h_net(z), g_net(z): independent -> one fused butterfly
    float e = softplus_f(fmaf(xn, ew1j, eb1j)) * ew2j;
    float h = softplus_f(fmaf(z,  hw1j, hb1j)) * hw2j;
    float g = softplus_f(fmaf(z,  gw1j, gb1j)) * gw2j;
    #pragma unroll
    for (int m = 1; m <= 32; m <<= 1) {
      e += __shfl_xor(e, m);
      h += __shfl_xor(h, m);
      g += __shfl_xor(g, m);
    }
    const float c  = e + eb2s;
    const float hv = h + hb2s;
    const float gv = 1.0f / (1.0f + __expf(-(g + gb2s)));

    // f_net([z, c]) depends on the encoder reduction
    float f = softplus_f(fmaf(z, fw1z, fmaf(c, fw1c, fb1j))) * fw2j;
    #pragma unroll
    for (int m = 1; m <= 32; m <<= 1) f += __shfl_xor(f, m);
    const float fv = f + fb2s;

    const float u = (fv - hv) / gv;
    lr_sum = fmaf(0.5f * dt, u * u, lr_sum);
    z = z + fv * dt + gv * dW[k * B_SZ + b] * sqdt;

    // projector on the new z
    float p = softplus_f(fmaf(z, pw1j, pb1j)) * pw2j;
    #pragma unroll
    for (int m = 1; m <= 32; m <<= 1) p += __shfl_xor(p, m);
    const float px = p + pb2s;
    const float d = (xn - px) * inv_ns;
    lp_sum = fmaf(-0.5f, d * d, lp_sum);
  }

  // constant terms: T * (-log(ns) - 0.5*log(2*pi))
  lp_sum += (float)T_SZ * (-__logf(ns) - 0.9189385332046727f);

  if (lane == 0) {
    outA[b] = lp_sum;         // per-b sum_t lp
    outB[b] = kl + lr_sum;    // per-b (kl + logqp_path)
  }
}

// Deterministic final reduction: one block, fixed order -> reproducible across
// graph replays (no float atomics).
__global__ __launch_bounds__(256) void reduce_final(
    const float* __restrict__ A, const float* __restrict__ Bv,
    float* __restrict__ out)
{
  __shared__ float la[256], lb[256];
  float sa = 0.0f, sb = 0.0f;
  for (int i = threadIdx.x; i < B_SZ; i += 256) { sa += A[i]; sb += Bv[i]; }
  la[threadIdx.x] = sa; lb[threadIdx.x] = sb;
  __syncthreads();
  for (int s = 128; s > 0; s >>= 1) {
    if (threadIdx.x < s) {
      la[threadIdx.x] += la[threadIdx.x + s];
      lb[threadIdx.x] += lb[threadIdx.x + s];
    }
    __syncthreads();
  }
  if (threadIdx.x == 0) {
    out[0] = la[0] / (float)B_SZ;
    out[1] = lb[0] / (float)B_SZ;
  }
}

extern "C" void kernel_launch(void* const* d_in, const int* in_sizes, int n_in,
                              void* d_out, int out_size, void* d_ws, size_t ws_size,
                              hipStream_t stream) {
  const float* xs        = (const float*)d_in[0];
  const float* ts        = (const float*)d_in[1];
  const float* noise_std = (const float*)d_in[2];
  const float* eps0      = (const float*)d_in[3];
  const float* dW        = (const float*)d_in[4];
  const float* ew1 = (const float*)d_in[5];
  const float* eb1 = (const float*)d_in[6];
  const float* ew2 = (const float*)d_in[7];
  const float* eb2 = (const float*)d_in[8];
  const float* qw  = (const float*)d_in[9];
  const float* qb  = (const float*)d_in[10];
  const float* fw1 = (const float*)d_in[11];
  const float* fb1 = (const float*)d_in[12];
  const float* fw2 = (const float*)d_in[13];
  const float* fb2 = (const float*)d_in[14];
  const float* hw1 = (const float*)d_in[15];
  const float* hb1 = (const float*)d_in[16];
  const float* hw2 = (const float*)d_in[17];
  const float* hb2 = (const float*)d_in[18];
  const float* gw1 = (const float*)d_in[19];
  const float* gb1 = (const float*)d_in[20];
  const float* gw2 = (const float*)d_in[21];
  const float* gb2 = (const float*)d_in[22];
  const float* pw1 = (const float*)d_in[23];
  const float* pb1 = (const float*)d_in[24];
  const float* pw2 = (const float*)d_in[25];
  const float* pb2 = (const float*)d_in[26];
  const float* pz0_mean   = (const float*)d_in[27];
  const float* pz0_logstd = (const float*)d_in[28];

  float* A  = (float*)d_ws;          // [B] per-b lp sums
  float* Bv = A + B_SZ;              // [B] per-b kl + path sums
  float* out = (float*)d_out;        // [2]

  // 4 waves/block, one wave per batch element
  sde_fused<<<B_SZ / 4, 256, 0, stream>>>(
      xs, ts, noise_std, eps0, dW,
      ew1, eb1, ew2, eb2, qw, qb,
      fw1, fb1, fw2, fb2, hw1, hb1, hw2, hb2,
      gw1, gb1, gw2, gb2, pw1, pb1, pw2, pb2,
      pz0_mean, pz0_logstd, A, Bv);

  reduce_final<<<1, 256, 0, stream>>>(A, Bv, out);
}

// Round 2
// 243.064 us; speedup vs baseline: 1.5502x; 1.5502x over previous
//
#include <hip/hip_runtime.h>
#include <math.h>

// LatentSDE, restructured in 4 phases:
//   1) enc_ctx:  ctx[t,b] = encoder(xs[t,b])      thread-per-(t,b), no shuffles
//   2) sde_scan: serial 127-step scan; 4 batch elements per wave (16-lane
//      groups, 4 hidden units/lane), f/h/g fused into one 3-wide 4-stage
//      ds_swizzle butterfly; stores z[t,b]
//   3) proj_lp:  projector likelihood over all (t,b), block partial sums
//   4) final_red: deterministic single-block reduction -> out[2]

#define B_SZ 8192
#define T_SZ 128
#define NPART (T_SZ * B_SZ / 256)   // 4096 projector blocks

__device__ __forceinline__ float softplus_f(float x) {
  // stable softplus: max(x,0) + log1p(exp(-|x|))
  return fmaxf(x, 0.0f) + __logf(1.0f + __expf(-fabsf(x)));
}

template <int PAT>
__device__ __forceinline__ float swz(float v) {
  return __int_as_float(__builtin_amdgcn_ds_swizzle(__float_as_int(v), PAT));
}

// ---------------- phase 1: encoder, pointwise in (t,b) ----------------
__global__ __launch_bounds__(256) void enc_ctx(
    const float* __restrict__ xs,
    const float* __restrict__ ew1, const float* __restrict__ eb1,
    const float* __restrict__ ew2, const float* __restrict__ eb2,
    float* __restrict__ ctx)
{
  __shared__ float w[192];
  const int tid = threadIdx.x;
  if (tid < 192) {
    const float* src = tid < 64 ? ew1 : (tid < 128 ? eb1 : ew2);
    w[tid] = src[tid & 63];
  }
  __syncthreads();
  const int i = blockIdx.x * 256 + tid;
  const float x = xs[i];
  float acc = 0.0f;
  #pragma unroll 8
  for (int u = 0; u < 64; ++u)
    acc = fmaf(softplus_f(fmaf(x, w[u], w[64 + u])), w[128 + u], acc);
  ctx[i] = acc + eb2[0];
}

// ---------------- phase 2: the serial scan ----------------
// 256 thr/block = 4 waves; wave serves 4 batch elements (16-lane groups).
__global__ __launch_bounds__(256) void sde_scan(
    const float* __restrict__ ts, const float* __restrict__ eps0,
    const float* __restrict__ dW, const float* __restrict__ ctx,
    const float* __restrict__ qw,  const float* __restrict__ qb,
    const float* __restrict__ fw1, const float* __restrict__ fb1,
    const float* __restrict__ fw2, const float* __restrict__ fb2,
    const float* __restrict__ hw1, const float* __restrict__ hb1,
    const float* __restrict__ hw2, const float* __restrict__ hb2,
    const float* __restrict__ gw1, const float* __restrict__ gb1,
    const float* __restrict__ gw2, const float* __restrict__ gb2,
    const float* __restrict__ pz0_mean, const float* __restrict__ pz0_logstd,
    float* __restrict__ zbuf, float* __restrict__ qp)
{
  const int tid  = threadIdx.x;
  const int wave = tid >> 6;
  const int lane = tid & 63;
  const int grp  = lane >> 4;     // which of 4 batch elements in this wave
  const int li   = lane & 15;     // position within 16-lane group
  const int b = blockIdx.x * 16 + wave * 4 + grp;

  // lane owns hidden units u*16+li, u=0..3, of f/h/g
  float fwz[4], fwc[4], fbv[4], fw2r[4];
  float hwv[4], hbv[4], hw2r[4];
  float gwv[4], gbv[4], gw2r[4];
  #pragma unroll
  for (int u = 0; u < 4; ++u) {
    const int h = u * 16 + li;
    fwz[u] = fw1[h]; fwc[u] = fw1[64 + h]; fbv[u] = fb1[h]; fw2r[u] = fw2[h];
    hwv[u] = hw1[h]; hbv[u] = hb1[h]; hw2r[u] = hw2[h];
    gwv[u] = gw1[h]; gbv[u] = gb1[h]; gw2r[u] = gw2[h];
  }
  const float fb2s = fb2[0], hb2s = hb2[0], gb2s = gb2[0];
  const float qw0 = qw[0], qw1 = qw[1], qb0 = qb[0], qb1 = qb[1];
  const float pm = pz0_mean[0], pls = pz0_logstd[0];

  // ---- z0, kl ----
  const float ctx0 = ctx[b];
  const float qm  = fmaf(ctx0, qw0, qb0);
  const float qls = fmaf(ctx0, qw1, qb1);
  float z = fmaf(__expf(qls), eps0[b], qm);
  const float dqm = qm - pm;
  const float kl = (pls - qls)
                 + (__expf(2.0f * qls) + dqm * dqm) / (2.0f * __expf(2.0f * pls))
                 - 0.5f;
  if (li == 0) zbuf[b] = z;

  float lr_sum = 0.0f;
  float c_cur  = ctx[B_SZ + b];   // ctx[k+1] for k=0
  float dw_cur = dW[b];

  for (int k = 0; k < T_SZ - 1; ++k) {
    // prefetch next step's operands (hides HBM/L2 latency under compute)
    float c_nxt = 0.0f, dw_nxt = 0.0f;
    if (k < T_SZ - 2) {
      c_nxt  = ctx[(k + 2) * B_SZ + b];
      dw_nxt = dW[(k + 1) * B_SZ + b];
    }
    const float dt   = ts[k + 1] - ts[k];
    const float sqdt = sqrtf(dt);

    // per-lane partials over 4 hidden units of each net (all independent)
    float sf = 0.0f, sh = 0.0f, sg = 0.0f;
    #pragma unroll
    for (int u = 0; u < 4; ++u) {
      sf = fmaf(softplus_f(fmaf(z, fwz[u], fmaf(c_cur, fwc[u], fbv[u]))), fw2r[u], sf);
      sh = fmaf(softplus_f(fmaf(z, hwv[u], hbv[u])), hw2r[u], sh);
      sg = fmaf(softplus_f(fmaf(z, gwv[u], gbv[u])), gw2r[u], sg);
    }
    // 3-wide butterfly within each 16-lane group: xor 1,2,4,8
    sf += swz<0x041F>(sf); sh += swz<0x041F>(sh); sg += swz<0x041F>(sg);
    sf += swz<0x081F>(sf); sh += swz<0x081F>(sh); sg += swz<0x081F>(sg);
    sf += swz<0x101F>(sf); sh += swz<0x101F>(sh); sg += swz<0x101F>(sg);
    sf += swz<0x201F>(sf); sh += swz<0x201F>(sh); sg += swz<0x201F>(sg);

    const float fv = sf + fb2s;
    const float hv = sh + hb2s;
    const float gv = 1.0f / (1.0f + __expf(-(sg + gb2s)));

    const float u  = (fv - hv) / gv;
    lr_sum = fmaf(0.5f * dt, u * u, lr_sum);
    z = z + fv * dt + gv * dw_cur * sqdt;
    if (li == 0) zbuf[(k + 1) * B_SZ + b] = z;

    c_cur = c_nxt; dw_cur = dw_nxt;
  }
  if (li == 0) qp[b] = kl + lr_sum;
}

// ---------------- phase 3: projector likelihood, pointwise ----------------
__global__ __launch_bounds__(256) void proj_lp(
    const float* __restrict__ xs, const float* __restrict__ zbuf,
    const float* __restrict__ noise_std,
    const float* __restrict__ pw1, const float* __restrict__ pb1,
    const float* __restrict__ pw2, const float* __restrict__ pb2,
    float* __restrict__ partials)
{
  __shared__ float w[192];
  __shared__ float red[256];
  const int tid = threadIdx.x;
  if (tid < 192) {
    const float* src = tid < 64 ? pw1 : (tid < 128 ? pb1 : pw2);
    w[tid] = src[tid & 63];
  }
  __syncthreads();
  const int i = blockIdx.x * 256 + tid;
  const float z = zbuf[i];
  const float x = xs[i];
  float acc = 0.0f;
  #pragma unroll 8
  for (int u = 0; u < 64; ++u)
    acc = fmaf(softplus_f(fmaf(z, w[u], w[64 + u])), w[128 + u], acc);
  const float px = acc + pb2[0];
  const float d = (x - px) * (1.0f / noise_std[0]);
  red[tid] = -0.5f * d * d;
  __syncthreads();
  for (int s = 128; s > 0; s >>= 1) {
    if (tid < s) red[tid] += red[tid + s];
    __syncthreads();
  }
  if (tid == 0) partials[blockIdx.x] = red[0];
}

// ---------------- phase 4: deterministic final reduction ----------------
__global__ __launch_bounds__(256) void final_red(
    const float* __restrict__ partials, const float* __restrict__ qp,
    const float* __restrict__ noise_std, float* __restrict__ out)
{
  __shared__ float la[256], lb[256];
  const int tid = threadIdx.x;
  float sa = 0.0f, sb = 0.0f;
  for (int i = tid; i < NPART; i += 256) sa += partials[i];
  for (int i = tid; i < B_SZ; i += 256) sb += qp[i];
  la[tid] = sa; lb[tid] = sb;
  __syncthreads();
  for (int s = 128; s > 0; s >>= 1) {
    if (tid < s) { la[tid] += la[tid + s]; lb[tid] += lb[tid + s]; }
    __syncthreads();
  }
  if (tid == 0) {
    const float ns = noise_std[0];
    out[0] = la[0] / (float)B_SZ
           + (float)T_SZ * (-__logf(ns) - 0.9189385332046727f);
    out[1] = lb[0] / (float)B_SZ;
  }
}

// ================= fallback (round-1 fused kernel, used only if ws too small)
__global__ __launch_bounds__(256) void sde_fused(
    const float* __restrict__ xs, const float* __restrict__ ts,
    const float* __restrict__ noise_std, const float* __restrict__ eps0,
    const float* __restrict__ dW,
    const float* __restrict__ ew1, const float* __restrict__ eb1,
    const float* __restrict__ ew2, const float* __restrict__ eb2,
    const float* __restrict__ qw,  const float* __restrict__ qb,
    const float* __restrict__ fw1, const float* __restrict__ fb1,
    const float* __restrict__ fw2, const float* __restrict__ fb2,
    const float* __restrict__ hw1, const float* __restrict__ hb1,
    const float* __restrict__ hw2, const float* __restrict__ hb2,
    const float* __restrict__ gw1, const float* __restrict__ gb1,
    const float* __restrict__ gw2, const float* __restrict__ gb2,
    const float* __restrict__ pw1, const float* __restrict__ pb1,
    const float* __restrict__ pw2, const float* __restrict__ pb2,
    const float* __restrict__ pz0_mean, const float* __restrict__ pz0_logstd,
    float* __restrict__ outA, float* __restrict__ outB)
{
  const int lane = threadIdx.x & 63;
  const int wave = threadIdx.x >> 6;
  const int b = blockIdx.x * 4 + wave;
  const float ew1j = ew1[lane], eb1j = eb1[lane], ew2j = ew2[lane];
  const float fw1z = fw1[lane], fw1c = fw1[64 + lane], fb1j = fb1[lane], fw2j = fw2[lane];
  const float hw1j = hw1[lane], hb1j = hb1[lane], hw2j = hw2[lane];
  const float gw1j = gw1[lane], gb1j = gb1[lane], gw2j = gw2[lane];
  const float pw1j = pw1[lane], pb1j = pb1[lane], pw2j = pw2[lane];
  const float eb2s = eb2[0], fb2s = fb2[0], hb2s = hb2[0], gb2s = gb2[0], pb2s = pb2[0];
  const float qw0 = qw[0], qw1 = qw[1], qb0 = qb[0], qb1 = qb[1];
  const float ns = noise_std[0];
  const float inv_ns = 1.0f / ns;
  const float pm = pz0_mean[0], pls = pz0_logstd[0];
  const float x0 = xs[b];
  float epre = softplus_f(fmaf(x0, ew1j, eb1j)) * ew2j;
  #pragma unroll
  for (int m = 1; m <= 32; m <<= 1) epre += __shfl_xor(epre, m);
  const float ctx0 = epre + eb2s;
  const float qm  = fmaf(ctx0, qw0, qb0);
  const float qls = fmaf(ctx0, qw1, qb1);
  float z = fmaf(__expf(qls), eps0[b], qm);
  const float dqm = qm - pm;
  const float kl = (pls - qls)
                 + (__expf(2.0f * qls) + dqm * dqm) / (2.0f * __expf(2.0f * pls))
                 - 0.5f;
  float lp_sum, lr_sum = 0.0f;
  {
    float p = softplus_f(fmaf(z, pw1j, pb1j)) * pw2j;
    #pragma unroll
    for (int m = 1; m <= 32; m <<= 1) p += __shfl_xor(p, m);
    const float px = p + pb2s;
    const float d = (x0 - px) * inv_ns;
    lp_sum = -0.5f * d * d;
  }
  for (int k = 0; k < T_SZ - 1; ++k) {
    const float xn   = xs[(k + 1) * B_SZ + b];
    const float dt   = ts[k + 1] - ts[k];
    const float sqdt = sqrtf(dt);
    float e = softplus_f(fmaf(xn, ew1j, eb1j)) * ew2j;
    float h = softplus_f(fmaf(z,  hw1j, hb1j)) * hw2j;
    float g = softplus_f(fmaf(z,  gw1j, gb1j)) * gw2j;
    #pragma unroll
    for (int m = 1; m <= 32; m <<= 1) {
      e += __shfl_xor(e, m);
      h += __shfl_xor(h, m);
      g += __shfl_xor(g, m);
    }
    const float c  = e + eb2s;
    const float hv = h + hb2s;
    const float gv = 1.0f / (1.0f + __expf(-(g + gb2s)));
    float f = softplus_f(fmaf(z, fw1z, fmaf(c, fw1c, fb1j))) * fw2j;
    #pragma unroll
    for (int m = 1; m <= 32; m <<= 1) f += __shfl_xor(f, m);
    const float fv = f + fb2s;
    const float u = (fv - hv) / gv;
    lr_sum = fmaf(0.5f * dt, u * u, lr_sum);
    z = z + fv * dt + gv * dW[k * B_SZ + b] * sqdt;
    float p = softplus_f(fmaf(z, pw1j, pb1j)) * pw2j;
    #pragma unroll
    for (int m = 1; m <= 32; m <<= 1) p += __shfl_xor(p, m);
    const float px = p + pb2s;
    const float d = (xn - px) * inv_ns;
    lp_sum = fmaf(-0.5f, d * d, lp_sum);
  }
  lp_sum += (float)T_SZ * (-__logf(ns) - 0.9189385332046727f);
  if (lane == 0) { outA[b] = lp_sum; outB[b] = kl + lr_sum; }
}

__global__ __launch_bounds__(256) void reduce_final(
    const float* __restrict__ A, const float* __restrict__ Bv,
    float* __restrict__ out)
{
  __shared__ float la[256], lb[256];
  float sa = 0.0f, sb = 0.0f;
  for (int i = threadIdx.x; i < B_SZ; i += 256) { sa += A[i]; sb += Bv[i]; }
  la[threadIdx.x] = sa; lb[threadIdx.x] = sb;
  __syncthreads();
  for (int s = 128; s > 0; s >>= 1) {
    if (threadIdx.x < s) {
      la[threadIdx.x] += la[threadIdx.x + s];
      lb[threadIdx.x] += lb[threadIdx.x + s];
    }
    __syncthreads();
  }
  if (threadIdx.x == 0) {
    out[0] = la[0] / (float)B_SZ;
    out[1] = lb[0] / (float)B_SZ;
  }
}

extern "C" void kernel_launch(void* const* d_in, const int* in_sizes, int n_in,
                              void* d_out, int out_size, void* d_ws, size_t ws_size,
                              hipStream_t stream) {
  const float* xs        = (const float*)d_in[0];
  const float* ts        = (const float*)d_in[1];
  const float* noise_std = (const float*)d_in[2];
  const float* eps0      = (const float*)d_in[3];
  const float* dW        = (const float*)d_in[4];
  const float* ew1 = (const float*)d_in[5];
  const float* eb1 = (const float*)d_in[6];
  const float* ew2 = (const float*)d_in[7];
  const float* eb2 = (const float*)d_in[8];
  const float* qw  = (const float*)d_in[9];
  const float* qb  = (const float*)d_in[10];
  const float* fw1 = (const float*)d_in[11];
  const float* fb1 = (const float*)d_in[12];
  const float* fw2 = (const float*)d_in[13];
  const float* fb2 = (const float*)d_in[14];
  const float* hw1 = (const float*)d_in[15];
  const float* hb1 = (const float*)d_in[16];
  const float* hw2 = (const float*)d_in[17];
  const float* hb2 = (const float*)d_in[18];
  const float* gw1 = (const float*)d_in[19];
  const float* gb1 = (const float*)d_in[20];
  const float* gw2 = (const float*)d_in[21];
  const float* gb2 = (const float*)d_in[22];
  const float* pw1 = (const float*)d_in[23];
  const float* pb1 = (const float*)d_in[24];
  const float* pw2 = (const float*)d_in[25];
  const float* pb2 = (const float*)d_in[26];
  const float* pz0_mean   = (const float*)d_in[27];
  const float* pz0_logstd = (const float*)d_in[28];
  float* out = (float*)d_out;

  const size_t need = (size_t)(2 * T_SZ * B_SZ + B_SZ + NPART) * sizeof(float);
  if (ws_size >= need) {
    float* ctx      = (float*)d_ws;               // [T*B]
    float* zbuf     = ctx + (size_t)T_SZ * B_SZ;  // [T*B]
    float* qp       = zbuf + (size_t)T_SZ * B_SZ; // [B]
    float* partials = qp + B_SZ;                  // [NPART]

    enc_ctx<<<T_SZ * B_SZ / 256, 256, 0, stream>>>(xs, ew1, eb1, ew2, eb2, ctx);
    sde_scan<<<B_SZ / 16, 256, 0, stream>>>(
        ts, eps0, dW, ctx, qw, qb,
        fw1, fb1, fw2, fb2, hw1, hb1, hw2, hb2,
        gw1, gb1, gw2, gb2, pz0_mean, pz0_logstd, zbuf, qp);
    proj_lp<<<NPART, 256, 0, stream>>>(xs, zbuf, noise_std, pw1, pb1, pw2, pb2, partials);
    final_red<<<1, 256, 0, stream>>>(partials, qp, noise_std, out);
  } else {
    float* A  = (float*)d_ws;
    float* Bv = A + B_SZ;
    sde_fused<<<B_SZ / 4, 256, 0, stream>>>(
        xs, ts, noise_std, eps0, dW,
        ew1, eb1, ew2, eb2, qw, qb,
        fw1, fb1, fw2, fb2, hw1, hb1, hw2, hb2,
        gw1, gb1, gw2, gb2, pw1, pb1, pw2, pb2,
        pz0_mean, pz0_logstd, A, Bv);
    reduce_final<<<1, 256, 0, stream>>>(A, Bv, out);
  }
}

// Round 3
// 119.532 us; speedup vs baseline: 3.1522x; 2.0335x over previous
//
#include <hip/hip_runtime.h>
#include <math.h>

// LatentSDE fully fused: one wave serves 4 batch elements (16-lane groups,
// 4 hidden units per lane per net). All five 64-unit MLPs evaluated per step;
// 16-lane reductions via DPP (quad_perm/mirror) adds -> no LDS, no lgkm waits.
// Encoder for step k+1 is computed during step k (off the z-dependency chain);
// projector runs after the z-update (feeds only an accumulator).

#define B_SZ 8192
#define T_SZ 128
#define LOG2E 1.4426950408889634f
#define LN2   0.6931471805599453f

#if __has_builtin(__builtin_amdgcn_exp2f)
#define EXP2F(x) __builtin_amdgcn_exp2f(x)
#else
#define EXP2F(x) __expf((x) * LN2)
#endif
#if __has_builtin(__builtin_amdgcn_logf)
#define LOG2F(x) __builtin_amdgcn_logf(x)
#else
#define LOG2F(x) (__logf(x) * LOG2E)
#endif
#if __has_builtin(__builtin_amdgcn_rcpf)
#define RCPF(x) __builtin_amdgcn_rcpf(x)
#else
#define RCPF(x) (1.0f / (x))
#endif
#if __has_builtin(__builtin_amdgcn_sqrtf)
#define SQRTF(x) __builtin_amdgcn_sqrtf(x)
#else
#define SQRTF(x) sqrtf(x)
#endif

template <int CTRL>
__device__ __forceinline__ float dpp_add(float v) {
  int t = __builtin_amdgcn_update_dpp(0, __float_as_int(v), CTRL, 0xF, 0xF, true);
  return v + __int_as_float(t);
}

// all-lanes sum over each 16-lane row: xor1, xor2, l^? via half-mirror+mirror
__device__ __forceinline__ float sum16(float v) {
  v = dpp_add<0xB1>(v);   // quad_perm [1,0,3,2]  (pair sums)
  v = dpp_add<0x4E>(v);   // quad_perm [2,3,0,1]  (quad sums)
  v = dpp_add<0x141>(v);  // row_half_mirror: l <-> 7-l  (8-sums)
  v = dpp_add<0x140>(v);  // row_mirror:      l <-> 15-l (16-sums)
  return v;
}

// softplus in log2 space: a2 = a*log2e; returns softplus(a)*log2e
__device__ __forceinline__ float sp2(float a2) {
  return fmaxf(a2, 0.0f) + LOG2F(1.0f + EXP2F(-fabsf(a2)));
}

__global__ __launch_bounds__(256) void sde_all(
    const float* __restrict__ xs, const float* __restrict__ ts,
    const float* __restrict__ noise_std, const float* __restrict__ eps0,
    const float* __restrict__ dW,
    const float* __restrict__ ew1, const float* __restrict__ eb1,
    const float* __restrict__ ew2, const float* __restrict__ eb2,
    const float* __restrict__ qw,  const float* __restrict__ qb,
    const float* __restrict__ fw1, const float* __restrict__ fb1,
    const float* __restrict__ fw2, const float* __restrict__ fb2,
    const float* __restrict__ hw1, const float* __restrict__ hb1,
    const float* __restrict__ hw2, const float* __restrict__ hb2,
    const float* __restrict__ gw1, const float* __restrict__ gb1,
    const float* __restrict__ gw2, const float* __restrict__ gb2,
    const float* __restrict__ pw1, const float* __restrict__ pb1,
    const float* __restrict__ pw2, const float* __restrict__ pb2,
    const float* __restrict__ pz0_mean, const float* __restrict__ pz0_logstd,
    float* __restrict__ outA, float* __restrict__ outB)
{
  const int tid  = threadIdx.x;
  const int li   = tid & 15;                 // position within 16-lane group
  const int b    = blockIdx.x * 16 + (tid >> 4);

  // per-lane weights for hidden units u*16+li; W1/b1 prescaled by log2e,
  // W2 by ln2 (g's W2 stays raw: its output goes straight into exp2).
  float ew1s[4], eb1s[4], ew2s[4];
  float fwzs[4], fwcs[4], fb1s[4], fw2s[4];
  float hw1s[4], hb1s[4], hw2s[4];
  float gw1s[4], gb1s[4], gw2r[4];
  float pw1s[4], pb1s[4], pw2s[4];
  #pragma unroll
  for (int u = 0; u < 4; ++u) {
    const int h = u * 16 + li;
    ew1s[u] = ew1[h] * LOG2E; eb1s[u] = eb1[h] * LOG2E; ew2s[u] = ew2[h] * LN2;
    fwzs[u] = fw1[h] * LOG2E; fwcs[u] = fw1[64 + h] * LOG2E;
    fb1s[u] = fb1[h] * LOG2E; fw2s[u] = fw2[h] * LN2;
    hw1s[u] = hw1[h] * LOG2E; hb1s[u] = hb1[h] * LOG2E; hw2s[u] = hw2[h] * LN2;
    gw1s[u] = gw1[h] * LOG2E; gb1s[u] = gb1[h] * LOG2E; gw2r[u] = gw2[h];
    pw1s[u] = pw1[h] * LOG2E; pb1s[u] = pb1[h] * LOG2E; pw2s[u] = pw2[h] * LN2;
  }
  const float eb2s = eb2[0], fb2s = fb2[0], hb2s = hb2[0], pb2s = pb2[0];
  const float gb2L = gb2[0] * LOG2E;
  const float qw0 = qw[0], qw1 = qw[1], qb0 = qb[0], qb1 = qb[1];
  const float ns = noise_std[0];
  const float inv_ns = 1.0f / ns;                 // one-time, precise
  const float nh_i2 = -0.5f * inv_ns * inv_ns;
  const float pm = pz0_mean[0], pls = pz0_logstd[0];

  auto enc = [&](float x) {
    float s = 0.0f;
    #pragma unroll
    for (int u = 0; u < 4; ++u)
      s = fmaf(sp2(fmaf(x, ew1s[u], eb1s[u])), ew2s[u], s);
    return sum16(s) + eb2s;
  };
  auto proj = [&](float zz) {
    float s = 0.0f;
    #pragma unroll
    for (int u = 0; u < 4; ++u)
      s = fmaf(sp2(fmaf(zz, pw1s[u], pb1s[u])), pw2s[u], s);
    return sum16(s) + pb2s;
  };

  // ---- prologue: z0, kl, lp(t=0) ----
  const float x0 = xs[b];
  float       x1 = xs[B_SZ + b];
  const float c0 = enc(x0);
  float    c_cur = enc(x1);
  const float qm  = fmaf(c0, qw0, qb0);
  const float qls = fmaf(c0, qw1, qb1);
  float z = fmaf(EXP2F(qls * LOG2E), eps0[b], qm);
  const float dqm = qm - pm;
  const float kl = (pls - qls)
                 + (EXP2F(2.0f * qls * LOG2E) + dqm * dqm)
                   * (0.5f * EXP2F(-2.0f * pls * LOG2E))
                 - 0.5f;
  float lp_sum;
  { const float px = proj(z); const float d = x0 - px; lp_sum = nh_i2 * d * d; }
  float dw_cur = dW[b];
  float lr_sum = 0.0f;

  // ---- Euler-Maruyama scan ----
  for (int k = 0; k < T_SZ - 1; ++k) {
    const int   i2     = (k + 2 < T_SZ) ? (k + 2) : (T_SZ - 1);
    const float x2     = xs[i2 * B_SZ + b];                       // prefetch
    const float dw_nxt = (k + 1 < T_SZ - 1) ? dW[(k + 1) * B_SZ + b] : 0.0f;
    const float dt     = ts[k + 1] - ts[k];
    const float sqdt   = SQRTF(dt);

    // f/h/g on (z, c_cur); encoder for the NEXT step on x2 (z-independent)
    float sf = 0.0f, sh = 0.0f, sg = 0.0f, se = 0.0f;
    #pragma unroll
    for (int u = 0; u < 4; ++u) {
      sf = fmaf(sp2(fmaf(z, fwzs[u], fmaf(c_cur, fwcs[u], fb1s[u]))), fw2s[u], sf);
      sh = fmaf(sp2(fmaf(z, hw1s[u], hb1s[u])), hw2s[u], sh);
      sg = fmaf(sp2(fmaf(z, gw1s[u], gb1s[u])), gw2r[u], sg);
      se = fmaf(sp2(fmaf(x2, ew1s[u], eb1s[u])), ew2s[u], se);
    }
    const float fv    = sum16(sf) + fb2s;
    const float hv    = sum16(sh) + hb2s;
    const float a2g   = sum16(sg) + gb2L;      // sigmoid arg * log2e
    const float c_nxt = sum16(se) + eb2s;

    const float t  = 1.0f + EXP2F(-a2g);       // t = 1/gv  (no division!)
    const float gv = RCPF(t);
    const float uu = (fv - hv) * t;            // == (fv-hv)/gv
    lr_sum = fmaf((0.5f * dt) * uu, uu, lr_sum);
    z = fmaf(gv * dw_cur, sqdt, fmaf(fv, dt, z));

    // projector on the new z; lp uses xs[k+1] (= x1)
    const float px = proj(z);
    const float d  = x1 - px;
    lp_sum = fmaf(nh_i2 * d, d, lp_sum);

    x1 = x2; c_cur = c_nxt; dw_cur = dw_nxt;
  }

  if (li == 0) {
    outA[b] = lp_sum;          // sum_t lp(t,b)  (constants added at reduce)
    outB[b] = kl + lr_sum;     // kl + logqp_path
  }
}

// deterministic single-block final reduction
__global__ __launch_bounds__(256) void final_red(
    const float* __restrict__ A, const float* __restrict__ Bv,
    const float* __restrict__ noise_std, float* __restrict__ out)
{
  __shared__ float la[256], lb[256];
  const int tid = threadIdx.x;
  float sa = 0.0f, sb = 0.0f;
  for (int i = tid; i < B_SZ; i += 256) { sa += A[i]; sb += Bv[i]; }
  la[tid] = sa; lb[tid] = sb;
  __syncthreads();
  for (int s = 128; s > 0; s >>= 1) {
    if (tid < s) { la[tid] += la[tid + s]; lb[tid] += lb[tid + s]; }
    __syncthreads();
  }
  if (tid == 0) {
    const float ns = noise_std[0];
    out[0] = la[0] / (float)B_SZ
           + (float)T_SZ * (-__logf(ns) - 0.9189385332046727f);
    out[1] = lb[0] / (float)B_SZ;
  }
}

extern "C" void kernel_launch(void* const* d_in, const int* in_sizes, int n_in,
                              void* d_out, int out_size, void* d_ws, size_t ws_size,
                              hipStream_t stream) {
  const float* xs        = (const float*)d_in[0];
  const float* ts        = (const float*)d_in[1];
  const float* noise_std = (const float*)d_in[2];
  const float* eps0      = (const float*)d_in[3];
  const float* dW        = (const float*)d_in[4];
  const float* ew1 = (const float*)d_in[5];
  const float* eb1 = (const float*)d_in[6];
  const float* ew2 = (const float*)d_in[7];
  const float* eb2 = (const float*)d_in[8];
  const float* qw  = (const float*)d_in[9];
  const float* qb  = (const float*)d_in[10];
  const float* fw1 = (const float*)d_in[11];
  const float* fb1 = (const float*)d_in[12];
  const float* fw2 = (const float*)d_in[13];
  const float* fb2 = (const float*)d_in[14];
  const float* hw1 = (const float*)d_in[15];
  const float* hb1 = (const float*)d_in[16];
  const float* hw2 = (const float*)d_in[17];
  const float* hb2 = (const float*)d_in[18];
  const float* gw1 = (const float*)d_in[19];
  const float* gb1 = (const float*)d_in[20];
  const float* gw2 = (const float*)d_in[21];
  const float* gb2 = (const float*)d_in[22];
  const float* pw1 = (const float*)d_in[23];
  const float* pb1 = (const float*)d_in[24];
  const float* pw2 = (const float*)d_in[25];
  const float* pb2 = (const float*)d_in[26];
  const float* pz0_mean   = (const float*)d_in[27];
  const float* pz0_logstd = (const float*)d_in[28];
  float* out = (float*)d_out;

  float* A  = (float*)d_ws;   // [B]
  float* Bv = A + B_SZ;       // [B]

  sde_all<<<B_SZ / 16, 256, 0, stream>>>(
      xs, ts, noise_std, eps0, dW,
      ew1, eb1, ew2, eb2, qw, qb,
      fw1, fb1, fw2, fb2, hw1, hb1, hw2, hb2,
      gw1, gb1, gw2, gb2, pw1, pb1, pw2, pb2,
      pz0_mean, pz0_logstd, A, Bv);

  final_red<<<1, 256, 0, stream>>>(A, Bv, noise_std, out);
}

// Round 5
// 112.378 us; speedup vs baseline: 3.3529x; 1.0637x over previous
//
#include <hip/hip_runtime.h>
#include <math.h>

// LatentSDE: L=C=D=1, H=64 -> h(z), g(z), p(z), enc(x) are scalar->scalar
// smooth functions. Pre-tabulate them exactly (build_tabs), stage in LDS,
// and the 127-step scan interpolates (broadcast LDS reads). Only f(z,c) is
// 2-input -> computed exactly (4 units/lane, 16-lane DPP reduce).
// One wave serves 4 batch elements (16-lane groups).
// R4 bug fixed: encoder-table branch boundary (was TAB_FLOATS-(NZ+1), which
// excluded ALL encoder gids -> table stayed 0xAA poison -> ctx ~= 0).

#define B_SZ 8192
#define T_SZ 128
#define NZ   4096               // z-grid intervals, entries NZ+1
#define NX   2048               // x-grid intervals, entries NX+1
#define ZSCALE 32.0f            // z in [-64,64], dz = 1/32
#define ZOFF   2048.0f          // -ZLO*ZSCALE
#define XSCALE 128.0f           // x in [-8,8], dx = 1/128
#define XOFF   1024.0f
#define TAB_FLOATS (3*(NZ+1) + (NX+1))   // hg(interleaved) | p | e = 14340

#define LOG2E 1.4426950408889634f
#define LN2   0.6931471805599453f

#if __has_builtin(__builtin_amdgcn_exp2f)
#define EXP2F(x) __builtin_amdgcn_exp2f(x)
#else
#define EXP2F(x) __expf((x) * LN2)
#endif
#if __has_builtin(__builtin_amdgcn_logf)
#define LOG2F(x) __builtin_amdgcn_logf(x)
#else
#define LOG2F(x) (__logf(x) * LOG2E)
#endif
#if __has_builtin(__builtin_amdgcn_rcpf)
#define RCPF(x) __builtin_amdgcn_rcpf(x)
#else
#define RCPF(x) (1.0f / (x))
#endif
#if __has_builtin(__builtin_amdgcn_sqrtf)
#define SQRTF(x) __builtin_amdgcn_sqrtf(x)
#else
#define SQRTF(x) sqrtf(x)
#endif

template <int CTRL>
__device__ __forceinline__ float dpp_add(float v) {
  int t = __builtin_amdgcn_update_dpp(0, __float_as_int(v), CTRL, 0xF, 0xF, true);
  return v + __int_as_float(t);
}
__device__ __forceinline__ float sum16(float v) {
  v = dpp_add<0xB1>(v);   // pair
  v = dpp_add<0x4E>(v);   // quad
  v = dpp_add<0x141>(v);  // row_half_mirror -> 8
  v = dpp_add<0x140>(v);  // row_mirror -> 16
  return v;
}
// softplus in log2 space: input a*log2e, output softplus(a)*log2e
__device__ __forceinline__ float sp2(float a2) {
  return fmaxf(a2, 0.0f) + LOG2F(1.0f + EXP2F(-fabsf(a2)));
}
// precise softplus for table build
__device__ __forceinline__ float sp_precise(float a) {
  return fmaxf(a, 0.0f) + log1pf(expf(-fabsf(a)));
}

// ---------------- table build: 14340 exact 64-unit evaluations ----------------
__global__ __launch_bounds__(256) void build_tabs(
    const float* __restrict__ hw1, const float* __restrict__ hb1,
    const float* __restrict__ hw2, const float* __restrict__ hb2,
    const float* __restrict__ gw1, const float* __restrict__ gb1,
    const float* __restrict__ gw2, const float* __restrict__ gb2,
    const float* __restrict__ pw1, const float* __restrict__ pb1,
    const float* __restrict__ pw2, const float* __restrict__ pb2,
    const float* __restrict__ ew1, const float* __restrict__ eb1,
    const float* __restrict__ ew2, const float* __restrict__ eb2,
    float* __restrict__ tabs)
{
  const int gid = blockIdx.x * 256 + threadIdx.x;
  float* hgt = tabs;                    // interleaved (h, g), 2*(NZ+1)
  float* pt  = tabs + 2 * (NZ + 1);
  float* et  = pt + (NZ + 1);
  if (gid < 3 * (NZ + 1)) {
    const int net = gid / (NZ + 1);
    const int i   = gid - net * (NZ + 1);
    const float z = -64.0f + (float)i * (1.0f / ZSCALE);
    if (net == 0) {
      float s = 0.0f;
      for (int j = 0; j < 64; ++j)
        s = fmaf(sp_precise(fmaf(z, hw1[j], hb1[j])), hw2[j], s);
      hgt[2 * i] = s + hb2[0];
    } else if (net == 1) {
      float s = 0.0f;
      for (int j = 0; j < 64; ++j)
        s = fmaf(sp_precise(fmaf(z, gw1[j], gb1[j])), gw2[j], s);
      hgt[2 * i + 1] = 1.0f / (1.0f + expf(-(s + gb2[0])));
    } else {
      float s = 0.0f;
      for (int j = 0; j < 64; ++j)
        s = fmaf(sp_precise(fmaf(z, pw1[j], pb1[j])), pw2[j], s);
      pt[i] = s + pb2[0];
    }
  } else if (gid < TAB_FLOATS) {        // encoder entries: [3*(NZ+1), TAB_FLOATS)
    const int i = gid - 3 * (NZ + 1);
    const float x = -8.0f + (float)i * (1.0f / XSCALE);
    float s = 0.0f;
    for (int j = 0; j < 64; ++j)
      s = fmaf(sp_precise(fmaf(x, ew1[j], eb1[j])), ew2[j], s);
    et[i] = s + eb2[0];
  }
}

// ---------------- the fused scan ----------------
__global__ __launch_bounds__(256) void sde_all(
    const float* __restrict__ xs, const float* __restrict__ ts,
    const float* __restrict__ noise_std, const float* __restrict__ eps0,
    const float* __restrict__ dW,
    const float* __restrict__ qw,  const float* __restrict__ qb,
    const float* __restrict__ fw1, const float* __restrict__ fb1,
    const float* __restrict__ fw2, const float* __restrict__ fb2,
    const float* __restrict__ pz0_mean, const float* __restrict__ pz0_logstd,
    const float* __restrict__ tabsrc,
    float* __restrict__ outA, float* __restrict__ outB)
{
  __shared__ float tabs[TAB_FLOATS];
  const int tid = threadIdx.x;
  for (int j = tid; j < TAB_FLOATS; j += 256) tabs[j] = tabsrc[j];

  const float2* hgt = (const float2*)tabs;
  const float*  pt  = tabs + 2 * (NZ + 1);
  const float*  et  = pt + (NZ + 1);

  const int li = tid & 15;
  const int b  = blockIdx.x * 16 + (tid >> 4);

  // f-net per-lane weights (units u*16+li), log2-space prescaled
  float fwzs[4], fwcs[4], fb1s[4], fw2s[4];
  #pragma unroll
  for (int u = 0; u < 4; ++u) {
    const int h = u * 16 + li;
    fwzs[u] = fw1[h] * LOG2E; fwcs[u] = fw1[64 + h] * LOG2E;
    fb1s[u] = fb1[h] * LOG2E; fw2s[u] = fw2[h] * LN2;
  }
  const float fb2s = fb2[0];
  const float qw0 = qw[0], qw1 = qw[1], qb0 = qb[0], qb1 = qb[1];
  const float ns = noise_std[0];
  const float inv_ns = 1.0f / ns;
  const float nh_i2 = -0.5f * inv_ns * inv_ns;
  const float pm = pz0_mean[0], pls = pz0_logstd[0];

  __syncthreads();

  auto einterp = [&](float x) {
    const float s = fmaf(x, XSCALE, XOFF);
    int i = (int)floorf(s);
    i = min(max(i, 0), NX - 1);
    const float fr = s - (float)i;
    const float e0 = et[i], e1 = et[i + 1];
    return fmaf(fr, e1 - e0, e0);
  };

  // ---- prologue ----
  const float x0 = xs[b];
  float       x1 = xs[B_SZ + b];
  const float c0 = einterp(x0);
  float    c_cur = einterp(x1);
  const float qm  = fmaf(c0, qw0, qb0);
  const float qls = fmaf(c0, qw1, qb1);
  float z = fmaf(EXP2F(qls * LOG2E), eps0[b], qm);
  const float dqm = qm - pm;
  const float kl = (pls - qls)
                 + (EXP2F(2.0f * qls * LOG2E) + dqm * dqm)
                   * (0.5f * EXP2F(-2.0f * pls * LOG2E))
                 - 0.5f;

  // z0 table index + projector lp(t=0)
  float zs = fmaf(z, ZSCALE, ZOFF);
  int   zi = (int)floorf(zs);
  zi = min(max(zi, 0), NZ - 1);
  float zf = zs - (float)zi;
  float lp_sum;
  {
    const float p0 = pt[zi], p1 = pt[zi + 1];
    const float px = fmaf(zf, p1 - p0, p0);
    const float d = x0 - px;
    lp_sum = nh_i2 * d * d;
  }
  float dw_cur = dW[b];
  float lr_sum = 0.0f;

  // ---- Euler-Maruyama scan ----
  for (int k = 0; k < T_SZ - 1; ++k) {
    const int   i2     = (k + 2 < T_SZ) ? (k + 2) : (T_SZ - 1);
    const float x2     = xs[i2 * B_SZ + b];
    const float dw_nxt = (k + 1 < T_SZ - 1) ? dW[(k + 1) * B_SZ + b] : 0.0f;
    const float dt     = ts[k + 1] - ts[k];
    const float sqdt   = SQRTF(dt);

    // h(z), g(z) via one broadcast LDS float2 interp (all 16 lanes same addr)
    const float2 a = hgt[zi], bb = hgt[zi + 1];
    const float hv = fmaf(zf, bb.x - a.x, a.x);
    float gv       = fmaf(zf, bb.y - a.y, a.y);
    gv = fminf(fmaxf(gv, 1e-7f), 1.0f);

    // f(z, c): exact, 4 units/lane + DPP reduce
    float sf = 0.0f;
    #pragma unroll
    for (int u = 0; u < 4; ++u)
      sf = fmaf(sp2(fmaf(z, fwzs[u], fmaf(c_cur, fwcs[u], fb1s[u]))), fw2s[u], sf);
    const float fv = sum16(sf) + fb2s;

    // encoder for next step (z-independent)
    const float c_nxt = einterp(x2);

    const float inv_gv = RCPF(gv);
    const float uu = (fv - hv) * inv_gv;
    lr_sum = fmaf((0.5f * dt) * uu, uu, lr_sum);
    z = fmaf(gv * dw_cur, sqdt, fmaf(fv, dt, z));

    // new z index (shared by projector now and h/g next iter)
    zs = fmaf(z, ZSCALE, ZOFF);
    zi = (int)floorf(zs);
    zi = min(max(zi, 0), NZ - 1);
    zf = zs - (float)zi;

    // projector likelihood at t=k+1
    const float p0 = pt[zi], p1 = pt[zi + 1];
    const float px = fmaf(zf, p1 - p0, p0);
    const float d = x1 - px;
    lp_sum = fmaf(nh_i2 * d, d, lp_sum);

    x1 = x2; c_cur = c_nxt; dw_cur = dw_nxt;
  }

  if (li == 0) {
    outA[b] = lp_sum;
    outB[b] = kl + lr_sum;
  }
}

// deterministic single-block final reduction
__global__ __launch_bounds__(256) void final_red(
    const float* __restrict__ A, const float* __restrict__ Bv,
    const float* __restrict__ noise_std, float* __restrict__ out)
{
  __shared__ float la[256], lb[256];
  const int tid = threadIdx.x;
  float sa = 0.0f, sb = 0.0f;
  for (int i = tid; i < B_SZ; i += 256) { sa += A[i]; sb += Bv[i]; }
  la[tid] = sa; lb[tid] = sb;
  __syncthreads();
  for (int s = 128; s > 0; s >>= 1) {
    if (tid < s) { la[tid] += la[tid + s]; lb[tid] += lb[tid + s]; }
    __syncthreads();
  }
  if (tid == 0) {
    const float ns = noise_std[0];
    out[0] = la[0] / (float)B_SZ
           + (float)T_SZ * (-__logf(ns) - 0.9189385332046727f);
    out[1] = lb[0] / (float)B_SZ;
  }
}

extern "C" void kernel_launch(void* const* d_in, const int* in_sizes, int n_in,
                              void* d_out, int out_size, void* d_ws, size_t ws_size,
                              hipStream_t stream) {
  const float* xs        = (const float*)d_in[0];
  const float* ts        = (const float*)d_in[1];
  const float* noise_std = (const float*)d_in[2];
  const float* eps0      = (const float*)d_in[3];
  const float* dW        = (const float*)d_in[4];
  const float* ew1 = (const float*)d_in[5];
  const float* eb1 = (const float*)d_in[6];
  const float* ew2 = (const float*)d_in[7];
  const float* eb2 = (const float*)d_in[8];
  const float* qw  = (const float*)d_in[9];
  const float* qb  = (const float*)d_in[10];
  const float* fw1 = (const float*)d_in[11];
  const float* fb1 = (const float*)d_in[12];
  const float* fw2 = (const float*)d_in[13];
  const float* fb2 = (const float*)d_in[14];
  const float* hw1 = (const float*)d_in[15];
  const float* hb1 = (const float*)d_in[16];
  const float* hw2 = (const float*)d_in[17];
  const float* hb2 = (const float*)d_in[18];
  const float* gw1 = (const float*)d_in[19];
  const float* gb1 = (const float*)d_in[20];
  const float* gw2 = (const float*)d_in[21];
  const float* gb2 = (const float*)d_in[22];
  const float* pw1 = (const float*)d_in[23];
  const float* pb1 = (const float*)d_in[24];
  const float* pw2 = (const float*)d_in[25];
  const float* pb2 = (const float*)d_in[26];
  const float* pz0_mean   = (const float*)d_in[27];
  const float* pz0_logstd = (const float*)d_in[28];
  float* out = (float*)d_out;

  float* tabs = (float*)d_ws;               // [TAB_FLOATS]
  float* A    = tabs + TAB_FLOATS;          // [B]
  float* Bv   = A + B_SZ;                   // [B]

  build_tabs<<<(TAB_FLOATS + 255) / 256, 256, 0, stream>>>(
      hw1, hb1, hw2, hb2, gw1, gb1, gw2, gb2,
      pw1, pb1, pw2, pb2, ew1, eb1, ew2, eb2, tabs);

  sde_all<<<B_SZ / 16, 256, 0, stream>>>(
      xs, ts, noise_std, eps0, dW, qw, qb,
      fw1, fb1, fw2, fb2, pz0_mean, pz0_logstd, tabs, A, Bv);

  final_red<<<1, 256, 0, stream>>>(A, Bv, noise_std, out);
}